// Round 9
// baseline (609.010 us; speedup 1.0000x reference)
//
#include <hip/hip_runtime.h>
#include <hip/hip_bf16.h>

#define TOK 4096
#define HD 1024
#define ID 512
#define NE 64
#define TK 8
#define CAP 1024
#define NROUTE 32768   // TOK*TK
#define NCHUNK 128     // NROUTE/256

typedef __attribute__((ext_vector_type(4))) float f32x4;
typedef __attribute__((ext_vector_type(8))) short s16x8;
typedef __attribute__((ext_vector_type(2))) __bf16 bf16x2;

__device__ __forceinline__ ushort f2bf(float f){
  uint u = __builtin_bit_cast(uint, f);
  u += 0x7fffu + ((u >> 16) & 1u);
  return (ushort)(u >> 16);
}
__device__ __forceinline__ float bf2f(ushort b){
  uint u = ((uint)b) << 16;
  return __builtin_bit_cast(float, u);
}
__device__ __forceinline__ uint2 f4_to_bf4(float4 v){
  bf16x2 p0; p0[0] = (__bf16)v.x; p0[1] = (__bf16)v.y;
  bf16x2 p1; p1[0] = (__bf16)v.z; p1[1] = (__bf16)v.w;
  uint2 r; r.x = __builtin_bit_cast(uint, p0); r.y = __builtin_bit_cast(uint, p1);
  return r;
}
__device__ __forceinline__ short bfs(float f){
  __bf16 h = (__bf16)f;
  return __builtin_bit_cast(short, h);
}
__device__ __forceinline__ s16x8 pack8(float4 a, float4 b){
  s16x8 r;
  r[0]=bfs(a.x); r[1]=bfs(a.y); r[2]=bfs(a.z); r[3]=bfs(a.w);
  r[4]=bfs(b.x); r[5]=bfs(b.y); r[6]=bfs(b.z); r[7]=bfs(b.w);
  return r;
}
__device__ __forceinline__ void gld16(void* lds, const void* g){
  __builtin_amdgcn_global_load_lds((const __attribute__((address_space(1))) unsigned int*)g,
                                   (__attribute__((address_space(3))) unsigned int*)lds, 16, 0, 0);
}

// ---------------- X -> bf16 pre-convert --------------------------------------
__global__ __launch_bounds__(256)
void cvtX_kernel(const float* __restrict__ X, ushort* __restrict__ Xbf){
  size_t i = ((size_t)blockIdx.x*256 + threadIdx.x) * 8;
  float4 a = *(const float4*)(X + i);
  float4 b = *(const float4*)(X + i + 4);
  uint2 lo = f4_to_bf4(a), hi = f4_to_bf4(b);
  uint4 o; o.x = lo.x; o.y = lo.y; o.z = hi.x; o.w = hi.y;
  *(uint4*)(Xbf + i) = o;
}

// ---------------- gating: fp64-accurate scores + top-8 + normalized weights --
__global__ __launch_bounds__(256)
void gating_kernel(const float* __restrict__ X, const float* __restrict__ GW,
                   int* __restrict__ topi, float* __restrict__ topw)
{
  __shared__ float xt[16][68];
  __shared__ float gt[64][68];
  __shared__ double ds[16][72];
  const int tid = threadIdx.x;
  const int tbase = blockIdx.x * 16;
  const int t = tid & 15, e0 = (tid >> 4) * 4;
  double acc[4] = {0.0, 0.0, 0.0, 0.0};
  for (int hc=0; hc<HD; hc+=64){
    { int r = tid >> 4, c4 = (tid & 15) * 4;
      *(float4*)&xt[r][c4] = *(const float4*)(X + (size_t)(tbase+r)*HD + hc + c4); }
    #pragma unroll
    for (int it=0; it<4; ++it){
      int idx = it*256 + tid;
      int r = idx >> 4, c4 = (idx & 15) * 4;
      *(float4*)&gt[r][c4] = *(const float4*)(GW + (size_t)r*HD + hc + c4);
    }
    __syncthreads();
    #pragma unroll
    for (int k4=0; k4<16; ++k4){
      float4 xv = *(const float4*)&xt[t][k4*4];
      #pragma unroll
      for (int j=0;j<4;++j){
        float4 gv = *(const float4*)&gt[e0+j][k4*4];
        acc[j] += (double)xv.x*(double)gv.x + (double)xv.y*(double)gv.y
                + (double)xv.z*(double)gv.z + (double)xv.w*(double)gv.w;
      }
    }
    __syncthreads();
  }
  #pragma unroll
  for (int j=0;j<4;++j) ds[t][e0+j] = acc[j];
  __syncthreads();
  if (tid < 16){
    int tt = tid;
    int idxs[8]; double vals[8]; double sum = 0.0;
    #pragma unroll
    for (int k=0;k<8;++k){
      double best = -1e300; int bi = 0;
      for (int e=0;e<NE;++e){ double v = ds[tt][e]; if (v > best){ best = v; bi = e; } }
      ds[tt][bi] = -1e300;
      double w = 1.0 / (1.0 + exp(-best));
      idxs[k] = bi; vals[k] = w; sum += w;
    }
    double inv = 1.0 / sum;
    #pragma unroll
    for (int k=0;k<8;++k){
      topi[(size_t)(tbase+tt)*TK + k] = idxs[k];
      topw[(size_t)(tbase+tt)*TK + k] = (float)(vals[k]*inv);
    }
  }
}

// ---------------- dispatch bookkeeping ---------------------------------------
__global__ __launch_bounds__(256)
void hist_kernel(const int* __restrict__ topi, int* __restrict__ ccnt){
  __shared__ int h[NE];
  const int tid = threadIdx.x;
  if (tid < NE) h[tid] = 0;
  __syncthreads();
  atomicAdd(&h[topi[blockIdx.x*256 + tid]], 1);
  __syncthreads();
  if (tid < NE) ccnt[blockIdx.x*NE + tid] = h[tid];
}

__global__ __launch_bounds__(64)
void scan_kernel(const int* __restrict__ ccnt, int* __restrict__ cbase,
                 int* __restrict__ cntC, int* __restrict__ ebase){
  const int e = threadIdx.x;
  int run = 0;
  for (int c=0;c<NCHUNK;++c){ cbase[c*NE+e] = run; run += ccnt[c*NE+e]; }
  cntC[e] = run < CAP ? run : CAP;
  __syncthreads();
  if (e == 0){
    int s = 0;
    for (int i=0;i<NE;++i){ ebase[i] = s; s += cntC[i]; }
    ebase[NE] = s;
  }
}

__global__ __launch_bounds__(64)
void assign_kernel(const int* __restrict__ topi, const int* __restrict__ cbase,
                   int* __restrict__ pos, int* __restrict__ rowlist){
  __shared__ int es[256];
  const int tid = threadIdx.x;
  const int c = blockIdx.x;
  for (int i=tid;i<256;i+=64) es[i] = topi[c*256+i];
  __syncthreads();
  const int e = tid;
  int cntr = cbase[c*NE+e];
  for (int j=0;j<256;++j){
    if (es[j] == e){
      int n = c*256+j;
      pos[n] = cntr;
      if (cntr < CAP) rowlist[e*CAP + cntr] = n;
      ++cntr;
    }
  }
}

// ---------------- grouped gate/up GEMM + fused SwiGLU (v7: B direct-to-reg) --
// Block 256 rows x 64 i-cols. 4 waves 2Mx2N; wave = 128 rows x (32g+32u rows).
// A: bf16 LDS dbuf via gld16, stage-at-top. B: loaded straight from global
// fp32 into MFMA fragment registers (no LDS), cvt at use. One barrier/step.
template<bool SHARED>
__global__ __launch_bounds__(256,2)
void gateup_kernel(const ushort* __restrict__ Xbf, const float* __restrict__ WG,
                   const float* __restrict__ WU, const int* __restrict__ rowlist,
                   const int* __restrict__ cntC, const int* __restrict__ ebase,
                   ushort* __restrict__ interm)
{
  int e, mt, nt, cnt, outbase;
  if (SHARED){
    nt = blockIdx.x & 7; mt = blockIdx.x >> 3; e = 0; cnt = TOK; outbase = mt*256;
  } else {
    int x = blockIdx.x & 7; int rem = blockIdx.x >> 3;
    nt = rem & 7; mt = (rem >> 3) & 3; e = ((rem >> 5) << 3) | x;  // e%8==bid%8 -> XCD locality
    cnt = cntC[e];
    if (mt*256 >= cnt) return;
    outbase = ebase[e] + mt*256;
  }
  const size_t wof = SHARED ? 0 : (size_t)e*ID*HD;
  const float* wg = WG + wof + (size_t)nt*64*HD;
  const float* wu = WU + wof + (size_t)nt*64*HD;

  __shared__ ushort aL[2][128*128];  // 2 x 32KB: 128 lines(=256 rows) x 16 gran
  __shared__ int tokb[256];

  const int tid = threadIdx.x;
  {
    int tokv;
    if (SHARED) tokv = mt*256 + tid;
    else tokv = (mt*256 + tid < cnt) ? (rowlist[e*CAP + mt*256 + tid] >> 3) : 0;
    tokb[tid] = tokv;
  }
  __syncthreads();

  const int w = tid >> 6, l = tid & 63;
  const int wm = w >> 1, wn = w & 1;     // 2M x 2N
  const int fr = l & 15, fko = (l >> 4) * 8;

  // A staging: 8 gld16 rounds x 256 lanes x 16B, inverse-swizzled global src
  uint aOff[8];
  #pragma unroll
  for (int j=0;j<8;++j){
    int f = j*256 + tid;
    int L = f >> 4, s = f & 15;
    int g = s ^ (L & 15);
    int r = 2*L + (g >> 3);
    aOff[j] = (uint)tokb[r]*HD + (uint)((g & 7)*8);
  }
  // B fragment base pointers: row = wn*32 + cg*16 + fr of the nt-slice
  const float* bp[2][2];
  #pragma unroll
  for (int mat=0;mat<2;++mat)
    #pragma unroll
    for (int cg=0;cg<2;++cg){
      int R = wn*32 + cg*16 + fr;
      bp[mat][cg] = (mat ? wu : wg) + (size_t)R*HD + fko;
    }

  f32x4 accg[8][2], accu[8][2];
  #pragma unroll
  for (int m=0;m<8;++m)
    #pragma unroll
    for (int c=0;c<2;++c){ accg[m][c] = (f32x4)0.0f; accu[m][c] = (f32x4)0.0f; }

  auto stageA = [&](int b, int kc){
    #pragma unroll
    for (int j=0;j<8;++j) gld16(&aL[b][(j*256 + w*64)*8], Xbf + aOff[j] + kc);
  };
  auto compute = [&](int b, int kc){
    // issue all 16 B loads first; compiler staggers vmcnt waits per fragment
    float4 bv[2][2][2][2];
    #pragma unroll
    for (int mat=0;mat<2;++mat)
      #pragma unroll
      for (int cg=0;cg<2;++cg)
        #pragma unroll
        for (int ks=0;ks<2;++ks){
          bv[mat][cg][ks][0] = *(const float4*)(bp[mat][cg] + kc + ks*32);
          bv[mat][cg][ks][1] = *(const float4*)(bp[mat][cg] + kc + ks*32 + 4);
        }
    s16x8 bfr[2][2][2];
    #pragma unroll
    for (int mat=0;mat<2;++mat)
      #pragma unroll
      for (int cg=0;cg<2;++cg)
        #pragma unroll
        for (int ks=0;ks<2;++ks)
          bfr[mat][cg][ks] = pack8(bv[mat][cg][ks][0], bv[mat][cg][ks][1]);
    #pragma unroll
    for (int ks=0;ks<2;++ks){
      int gk = ks*4 + (fko>>3);
      #pragma unroll
      for (int mb=0;mb<8;++mb){
        int r = wm*128 + mb*16 + fr;
        int L = r>>1, g = ((r&1)<<3)|gk;
        s16x8 a = *(const s16x8*)&aL[b][L*128 + (g^(L&15))*8];
        #pragma unroll
        for (int cg=0;cg<2;++cg){
          accg[mb][cg] = __builtin_amdgcn_mfma_f32_16x16x32_bf16(a, bfr[0][cg][ks], accg[mb][cg],0,0,0);
          accu[mb][cg] = __builtin_amdgcn_mfma_f32_16x16x32_bf16(a, bfr[1][cg][ks], accu[mb][cg],0,0,0);
        }
      }
    }
  };

  stageA(0, 0);
  __syncthreads();
  for (int t=0; t<16; ++t){
    const int cur = t & 1;
    if (t < 15) stageA(cur ^ 1, (t+1)*64);
    compute(cur, t*64);
    __syncthreads();
  }

  const int rq = (l >> 4) * 4;
  #pragma unroll
  for (int mb=0;mb<8;++mb){
    #pragma unroll
    for (int q=0;q<4;++q){
      int rloc = wm*128 + mb*16 + rq + q;
      if (!SHARED && mt*256 + rloc >= cnt) continue;
      size_t orow = (size_t)(outbase + rloc);
      #pragma unroll
      for (int cg=0;cg<2;++cg){
        float g = accg[mb][cg][q], u = accu[mb][cg][q];
        float sv = g / (1.0f + __expf(-g)) * u;   // silu(g)*u
        interm[orow*ID + (size_t)(nt*64 + wn*32 + cg*16 + fr)] = f2bf(sv);
      }
    }
  }
}

// ---------------- grouped down GEMM (v7: B direct-to-reg) --------------------
// Block 256 rows x 128 out-cols. 4 waves 2Mx2N; wave = 128 x 64. K=512.
template<bool SHARED>
__global__ __launch_bounds__(256,2)
void down_kernel(const ushort* __restrict__ interm, const float* __restrict__ WD,
                 const int* __restrict__ cntC, const int* __restrict__ ebase,
                 ushort* __restrict__ out_rows, float* __restrict__ outf)
{
  int e, mt, nt, cnt, abase;
  if (SHARED){
    nt = blockIdx.x & 7; mt = blockIdx.x >> 3; e = 0; cnt = TOK; abase = mt*256;
  } else {
    int x = blockIdx.x & 7; int rem = blockIdx.x >> 3;
    nt = rem & 7; mt = (rem >> 3) & 3; e = ((rem >> 5) << 3) | x;
    cnt = cntC[e];
    if (mt*256 >= cnt) return;
    abase = ebase[e] + mt*256;
  }
  const ushort* A = interm + (size_t)abase*ID;
  const float* wd = WD + (SHARED ? (size_t)0 : (size_t)e*HD*ID) + (size_t)nt*128*ID;

  __shared__ ushort aL[2][64*128];   // 2 x 16KB: 64 lines(=128... ) -- see below
  // NOTE: BM=256, BK=64 bf16 => 32KB per buffer: use [2][128*128]
  __shared__ ushort aL2[2][64*128];  // second half (contiguous with aL)

  const int tid = threadIdx.x;
  const int w = tid >> 6, l = tid & 63;
  const int wm = w >> 1, wn = w & 1;
  const int fr = l & 15, fko = (l >> 4) * 8;

  uint aOff[8];
  #pragma unroll
  for (int j=0;j<8;++j){
    int f = j*256 + tid;
    int L = f >> 4, s = f & 15;
    int g = s ^ (L & 15);
    int r = 2*L + (g >> 3);
    aOff[j] = (uint)r*ID + (uint)((g & 7)*8);
  }
  const float* bp[4];
  #pragma unroll
  for (int cg=0;cg<4;++cg){
    int R = wn*64 + cg*16 + fr;
    bp[cg] = wd + (size_t)R*ID + fko;
  }

  f32x4 acc[8][4];
  #pragma unroll
  for (int m=0;m<8;++m)
    #pragma unroll
    for (int c=0;c<4;++c) acc[m][c] = (f32x4)0.0f;

  auto ldsAt = [&](int b, int off)->ushort* {
    // buffer b spans aL[b] (first 8192 ushorts) then aL2[b]
    return (off < 64*128) ? &aL[b][off] : &aL2[b][off - 64*128];
  };
  auto stageA = [&](int b, int kc){
    #pragma unroll
    for (int j=0;j<8;++j) gld16(ldsAt(b, (j*256 + w*64)*8), A + aOff[j] + kc);
  };
  auto compute = [&](int b, int kc){
    float4 bv[4][2][2];
    #pragma unroll
    for (int cg=0;cg<4;++cg)
      #pragma unroll
      for (int ks=0;ks<2;++ks){
        bv[cg][ks][0] = *(const float4*)(bp[cg] + kc + ks*32);
        bv[cg][ks][1] = *(const float4*)(bp[cg] + kc + ks*32 + 4);
      }
    s16x8 bfr[4][2];
    #pragma unroll
    for (int cg=0;cg<4;++cg)
      #pragma unroll
      for (int ks=0;ks<2;++ks)
        bfr[cg][ks] = pack8(bv[cg][ks][0], bv[cg][ks][1]);
    #pragma unroll
    for (int ks=0;ks<2;++ks){
      int gk = ks*4 + (fko>>3);
      #pragma unroll
      for (int mb=0;mb<8;++mb){
        int r = wm*128 + mb*16 + fr;
        int L = r>>1, g = ((r&1)<<3)|gk;
        int off = L*128 + (g^(L&15))*8;
        s16x8 a = *(const s16x8*)ldsAt(b, off);
        #pragma unroll
        for (int cg=0;cg<4;++cg)
          acc[mb][cg] = __builtin_amdgcn_mfma_f32_16x16x32_bf16(a, bfr[cg][ks], acc[mb][cg],0,0,0);
      }
    }
  };

  stageA(0, 0);
  __syncthreads();
  for (int t=0; t<8; ++t){
    const int cur = t & 1;
    if (t < 7) stageA(cur ^ 1, (t+1)*64);
    compute(cur, t*64);
    __syncthreads();
  }

  const int rq = (l >> 4) * 4;
  #pragma unroll
  for (int mb=0;mb<8;++mb){
    #pragma unroll
    for (int q=0;q<4;++q){
      int rloc = wm*128 + mb*16 + rq + q;
      if (!SHARED && mt*256 + rloc >= cnt) continue;
      #pragma unroll
      for (int cg=0;cg<4;++cg){
        float v = acc[mb][cg][q];
        int colg = nt*128 + wn*64 + cg*16 + fr;
        if (SHARED) outf[(size_t)(mt*256 + rloc)*HD + colg] = v;
        else        out_rows[(size_t)(abase + rloc)*HD + colg] = f2bf(v);
      }
    }
  }
}

// ---------------- combine: out += sum_k topw * routed_row --------------------
__global__ __launch_bounds__(256)
void combine_kernel(const int* __restrict__ topi, const float* __restrict__ topw,
                    const int* __restrict__ pos, const int* __restrict__ ebase,
                    const ushort* __restrict__ out_rows, float* __restrict__ out)
{
  const int t = blockIdx.x;
  const int tid = threadIdx.x;
  __shared__ int rws[TK];
  __shared__ float wts[TK];
  if (tid < TK){
    int e = topi[(size_t)t*TK + tid];
    int p = pos[(size_t)t*TK + tid];
    rws[tid] = (p < CAP) ? (ebase[e] + p) : -1;
    wts[tid] = topw[(size_t)t*TK + tid];
  }
  __syncthreads();
  const int h0 = tid * 4;
  float4 acc = *(float4*)(out + (size_t)t*HD + h0);
  #pragma unroll
  for (int k=0;k<TK;++k){
    int r = rws[k];
    if (r < 0) continue;
    ushort4 v = *(const ushort4*)(out_rows + (size_t)r*HD + h0);
    float wk = wts[k];
    acc.x += wk*bf2f(v.x); acc.y += wk*bf2f(v.y);
    acc.z += wk*bf2f(v.z); acc.w += wk*bf2f(v.w);
  }
  *(float4*)(out + (size_t)t*HD + h0) = acc;
}

// ---------------- launch ------------------------------------------------------
extern "C" void kernel_launch(void* const* d_in, const int* in_sizes, int n_in,
                              void* d_out, int out_size, void* d_ws, size_t ws_size,
                              hipStream_t stream)
{
  (void)in_sizes; (void)n_in; (void)out_size; (void)ws_size;
  const float* X   = (const float*)d_in[0];
  const float* GW  = (const float*)d_in[1];
  const float* SWG = (const float*)d_in[2];
  const float* SWU = (const float*)d_in[3];
  const float* SWD = (const float*)d_in[4];
  const float* EWG = (const float*)d_in[5];
  const float* EWU = (const float*)d_in[6];
  const float* EWD = (const float*)d_in[7];
  float* OUT = (float*)d_out;

  char* p = (char*)d_ws;
  int*    topi    = (int*)p;      p += (size_t)NROUTE*4;
  float*  topw    = (float*)p;    p += (size_t)NROUTE*4;
  int*    pos     = (int*)p;      p += (size_t)NROUTE*4;
  int*    ccnt    = (int*)p;      p += (size_t)NCHUNK*NE*4;
  int*    cbase   = (int*)p;      p += (size_t)NCHUNK*NE*4;
  int*    cntC    = (int*)p;      p += 256;
  int*    ebase   = (int*)p;      p += 512;
  int*    rowlist = (int*)p;      p += (size_t)NE*CAP*4;
  ushort* Xbf     = (ushort*)p;   p += (size_t)TOK*HD*2;
  ushort* interm_r= (ushort*)p;   p += (size_t)(NROUTE+256)*ID*2;
  ushort* interm_s= (ushort*)p;   p += (size_t)TOK*ID*2;
  ushort* out_rows= (ushort*)p;   p += (size_t)NROUTE*HD*2;

  cvtX_kernel<<<TOK*HD/8/256, 256, 0, stream>>>(X, Xbf);
  gating_kernel<<<256, 256, 0, stream>>>(X, GW, topi, topw);
  hist_kernel<<<NCHUNK, 256, 0, stream>>>(topi, ccnt);
  scan_kernel<<<1, 64, 0, stream>>>(ccnt, cbase, cntC, ebase);
  assign_kernel<<<NCHUNK, 64, 0, stream>>>(topi, cbase, pos, rowlist);

  gateup_kernel<false><<<2048, 256, 0, stream>>>(Xbf, EWG, EWU, rowlist, cntC, ebase, interm_r);
  gateup_kernel<true ><<<128,  256, 0, stream>>>(Xbf, SWG, SWU, nullptr, nullptr, nullptr, interm_s);
  down_kernel<false><<<2048, 256, 0, stream>>>(interm_r, EWD, cntC, ebase, out_rows, nullptr);
  down_kernel<true ><<<128,  256, 0, stream>>>(interm_s, SWD, nullptr, nullptr, nullptr, OUT);

  combine_kernel<<<TOK, 256, 0, stream>>>(topi, topw, pos, ebase, out_rows, OUT);
}

// Round 10
// 391.613 us; speedup vs baseline: 1.5551x; 1.5551x over previous
//
#include <hip/hip_runtime.h>
#include <hip/hip_bf16.h>

#define TOK 4096
#define HD 1024
#define ID 512
#define NE 64
#define TK 8
#define CAP 1024
#define NROUTE 32768   // TOK*TK
#define NCHUNK 128     // NROUTE/256

typedef __attribute__((ext_vector_type(4))) float f32x4;
typedef __attribute__((ext_vector_type(8))) short s16x8;
typedef __attribute__((ext_vector_type(2))) __bf16 bf16x2;

__device__ __forceinline__ ushort f2bf(float f){
  uint u = __builtin_bit_cast(uint, f);
  u += 0x7fffu + ((u >> 16) & 1u);
  return (ushort)(u >> 16);
}
__device__ __forceinline__ float bf2f(ushort b){
  uint u = ((uint)b) << 16;
  return __builtin_bit_cast(float, u);
}
__device__ __forceinline__ uint2 f4_to_bf4(float4 v){
  bf16x2 p0; p0[0] = (__bf16)v.x; p0[1] = (__bf16)v.y;
  bf16x2 p1; p1[0] = (__bf16)v.z; p1[1] = (__bf16)v.w;
  uint2 r; r.x = __builtin_bit_cast(uint, p0); r.y = __builtin_bit_cast(uint, p1);
  return r;
}
__device__ __forceinline__ short bfs(float f){
  __bf16 h = (__bf16)f;
  return __builtin_bit_cast(short, h);
}
__device__ __forceinline__ s16x8 pack8(f32x4 a, f32x4 b){
  s16x8 r;
  r[0]=bfs(a[0]); r[1]=bfs(a[1]); r[2]=bfs(a[2]); r[3]=bfs(a[3]);
  r[4]=bfs(b[0]); r[5]=bfs(b[1]); r[6]=bfs(b[2]); r[7]=bfs(b[3]);
  return r;
}
__device__ __forceinline__ void gld16(void* lds, const void* g){
  __builtin_amdgcn_global_load_lds((const __attribute__((address_space(1))) unsigned int*)g,
                                   (__attribute__((address_space(3))) unsigned int*)lds, 16, 0, 0);
}

// ---------------- X -> bf16 pre-convert --------------------------------------
__global__ __launch_bounds__(256)
void cvtX_kernel(const float* __restrict__ X, ushort* __restrict__ Xbf){
  size_t i = ((size_t)blockIdx.x*256 + threadIdx.x) * 8;
  float4 a = *(const float4*)(X + i);
  float4 b = *(const float4*)(X + i + 4);
  uint2 lo = f4_to_bf4(a), hi = f4_to_bf4(b);
  uint4 o; o.x = lo.x; o.y = lo.y; o.z = hi.x; o.w = hi.y;
  *(uint4*)(Xbf + i) = o;
}

// ---------------- gating (fast, r5): 256 blocks x 16 tokens, fp64 accumulate -
__global__ __launch_bounds__(256)
void gating_kernel(const float* __restrict__ X, const float* __restrict__ GW,
                   int* __restrict__ topi, float* __restrict__ topw)
{
  __shared__ float xt[16][68];
  __shared__ float gt[64][68];
  __shared__ double ds[16][72];
  const int tid = threadIdx.x;
  const int tbase = blockIdx.x * 16;
  const int t = tid & 15, e0 = (tid >> 4) * 4;
  double acc[4] = {0.0, 0.0, 0.0, 0.0};
  for (int hc=0; hc<HD; hc+=64){
    { int r = tid >> 4, c4 = (tid & 15) * 4;
      *(float4*)&xt[r][c4] = *(const float4*)(X + (size_t)(tbase+r)*HD + hc + c4); }
    #pragma unroll
    for (int it=0; it<4; ++it){
      int idx = it*256 + tid;
      int r = idx >> 4, c4 = (idx & 15) * 4;
      *(float4*)&gt[r][c4] = *(const float4*)(GW + (size_t)r*HD + hc + c4);
    }
    __syncthreads();
    #pragma unroll
    for (int k4=0; k4<16; ++k4){
      float4 xv = *(const float4*)&xt[t][k4*4];
      #pragma unroll
      for (int j=0;j<4;++j){
        float4 gv = *(const float4*)&gt[e0+j][k4*4];
        acc[j] += (double)xv.x*(double)gv.x + (double)xv.y*(double)gv.y
                + (double)xv.z*(double)gv.z + (double)xv.w*(double)gv.w;
      }
    }
    __syncthreads();
  }
  #pragma unroll
  for (int j=0;j<4;++j) ds[t][e0+j] = acc[j];
  __syncthreads();
  if (tid < 16){
    int tt = tid;
    int idxs[8]; double vals[8]; double sum = 0.0;
    #pragma unroll
    for (int k=0;k<8;++k){
      double best = -1e300; int bi = 0;
      for (int e=0;e<NE;++e){ double v = ds[tt][e]; if (v > best){ best = v; bi = e; } }
      ds[tt][bi] = -1e300;
      double w = 1.0 / (1.0 + exp(-best));
      idxs[k] = bi; vals[k] = w; sum += w;
    }
    double inv = 1.0 / sum;
    #pragma unroll
    for (int k=0;k<8;++k){
      topi[(size_t)(tbase+tt)*TK + k] = idxs[k];
      topw[(size_t)(tbase+tt)*TK + k] = (float)(vals[k]*inv);
    }
  }
}

// ---------------- dispatch bookkeeping ---------------------------------------
__global__ __launch_bounds__(256)
void hist_kernel(const int* __restrict__ topi, int* __restrict__ ccnt){
  __shared__ int h[NE];
  const int tid = threadIdx.x;
  if (tid < NE) h[tid] = 0;
  __syncthreads();
  atomicAdd(&h[topi[blockIdx.x*256 + tid]], 1);
  __syncthreads();
  if (tid < NE) ccnt[blockIdx.x*NE + tid] = h[tid];
}

__global__ __launch_bounds__(64)
void scan_kernel(const int* __restrict__ ccnt, int* __restrict__ cbase,
                 int* __restrict__ cntC, int* __restrict__ ebase){
  const int e = threadIdx.x;
  int run = 0;
  for (int c=0;c<NCHUNK;++c){ cbase[c*NE+e] = run; run += ccnt[c*NE+e]; }
  cntC[e] = run < CAP ? run : CAP;
  __syncthreads();
  if (e == 0){
    int s = 0;
    for (int i=0;i<NE;++i){ ebase[i] = s; s += cntC[i]; }
    ebase[NE] = s;
  }
}

__global__ __launch_bounds__(64)
void assign_kernel(const int* __restrict__ topi, const int* __restrict__ cbase,
                   int* __restrict__ pos, int* __restrict__ rowlist){
  __shared__ int es[256];
  const int tid = threadIdx.x;
  const int c = blockIdx.x;
  for (int i=tid;i<256;i+=64) es[i] = topi[c*256+i];
  __syncthreads();
  const int e = tid;
  int cntr = cbase[c*NE+e];
  for (int j=0;j<256;++j){
    if (es[j] == e){
      int n = c*256+j;
      pos[n] = cntr;
      if (cntr < CAP) rowlist[e*CAP + cntr] = n;
      ++cntr;
    }
  }
}

// ---------------- grouped gate/up GEMM + fused SwiGLU (r4-best config) -------
// Block: 128 rows x 64 i-cols (both matrices), 4 waves 2x2; wave = 64 rows x
// (32 gate + 32 up cols). A: bf16, 2-row-packed lines, 16-slot XOR swizzle via
// gld16. B: fp32 in LDS, gld16, 16-slot XOR swizzle, pack8 at fragment read.
// 2-barrier loop, ~49KB LDS -> 3 blocks/CU (block-level TLP hides latency).
template<bool SHARED>
__global__ __launch_bounds__(256,2)
void gateup_kernel(const ushort* __restrict__ Xbf, const float* __restrict__ WG,
                   const float* __restrict__ WU, const int* __restrict__ rowlist,
                   const int* __restrict__ cntC, const int* __restrict__ ebase,
                   ushort* __restrict__ interm)
{
  int e, mt, nt, cnt, outbase;
  if (SHARED){
    nt = blockIdx.x & 7; mt = blockIdx.x >> 3; e = 0; cnt = TOK; outbase = mt*128;
  } else {
    int x = blockIdx.x & 7; int rem = blockIdx.x >> 3;
    nt = rem & 7; mt = (rem >> 3) & 7; e = ((rem >> 6) << 3) | x;  // e%8==bid%8 -> XCD locality
    cnt = cntC[e];
    if (mt*128 >= cnt) return;
    outbase = ebase[e] + mt*128;
  }
  const size_t wof = SHARED ? 0 : (size_t)e*ID*HD;
  const float* wg = WG + wof + (size_t)nt*64*HD;
  const float* wu = WU + wof + (size_t)nt*64*HD;

  __shared__ ushort aL[64*128];   // 16KB: 64 lines (=128 rows) x 16 granules
  __shared__ float  bF[128*64];   // 32KB fp32
  __shared__ int tokb[128];

  const int tid = threadIdx.x;
  if (tid < 128){
    int tokv;
    if (SHARED) tokv = mt*128 + tid;
    else tokv = (mt*128 + tid < cnt) ? (rowlist[e*CAP + mt*128 + tid] >> 3) : 0;
    tokb[tid] = tokv;
  }
  __syncthreads();

  const int w = tid >> 6, l = tid & 63;
  const int wm = w >> 1, wn = w & 1;
  const int fr = l & 15, fko = (l >> 4) * 8;

  // A staging sources: inverse-swizzled global addresses
  const ushort* aSrc[4];
  #pragma unroll
  for (int j=0;j<4;++j){
    int f = j*256 + tid;
    int L = f >> 4, s = f & 15;
    int g = s ^ (L & 15);
    int row = 2*L + (g >> 3);
    aSrc[j] = Xbf + (size_t)tokb[row]*HD + (g & 7)*8;
  }
  // B staging sources
  const float* bSrc[8];
  #pragma unroll
  for (int j=0;j<8;++j){
    int f = j*256 + tid;
    int R = f >> 4, s = f & 15;
    int g = s ^ (R & 15);
    const float* base = (j < 4) ? wg : wu;
    int r2 = (j < 4) ? R : (R - 64);
    bSrc[j] = base + (size_t)r2*HD + g*4;
  }

  f32x4 accg[4][2], accu[4][2];
  #pragma unroll
  for (int i=0;i<4;++i)
    #pragma unroll
    for (int j=0;j<2;++j){ accg[i][j] = (f32x4)0.0f; accu[i][j] = (f32x4)0.0f; }

  auto stage = [&](int kc){
    #pragma unroll
    for (int j=0;j<4;++j) gld16(aL + (size_t)(j*256 + w*64)*8, aSrc[j] + kc);
    #pragma unroll
    for (int j=0;j<8;++j) gld16(bF + (size_t)(j*256 + w*64)*4, bSrc[j] + kc);
  };

  stage(0);
  for (int kc=0; kc<HD; kc+=64){
    __syncthreads();   // drains vmcnt: staged tile visible
    #pragma unroll
    for (int ks=0; ks<2; ++ks){
      s16x8 a[4];
      #pragma unroll
      for (int mb=0; mb<4; ++mb){
        int r = wm*64 + mb*16 + fr;
        int agl = ks*4 + (fko >> 3);
        int g = ((r & 1) << 3) | agl;
        int L = r >> 1;
        int gs = g ^ (L & 15);
        a[mb] = *(const s16x8*)&aL[L*128 + gs*8];
      }
      #pragma unroll
      for (int cg=0; cg<2; ++cg){
        int Rg = wn*32 + cg*16 + fr;
        int gl0 = ks*8 + (fko >> 2);
        int x0 = Rg*64 + ((gl0 ^ (Rg & 15)) * 4);
        int x1 = Rg*64 + (((gl0+1) ^ (Rg & 15)) * 4);
        s16x8 bg = pack8(*(const f32x4*)&bF[x0], *(const f32x4*)&bF[x1]);
        int Ru = 64 + wn*32 + cg*16 + fr;
        int y0 = Ru*64 + ((gl0 ^ (Ru & 15)) * 4);
        int y1 = Ru*64 + (((gl0+1) ^ (Ru & 15)) * 4);
        s16x8 bu = pack8(*(const f32x4*)&bF[y0], *(const f32x4*)&bF[y1]);
        #pragma unroll
        for (int mb=0; mb<4; ++mb){
          accg[mb][cg] = __builtin_amdgcn_mfma_f32_16x16x32_bf16(a[mb], bg, accg[mb][cg], 0, 0, 0);
          accu[mb][cg] = __builtin_amdgcn_mfma_f32_16x16x32_bf16(a[mb], bu, accu[mb][cg], 0, 0, 0);
        }
      }
    }
    __syncthreads();
    if (kc + 64 < HD) stage(kc + 64);
  }

  const int rq = (l >> 4) * 4;
  #pragma unroll
  for (int mb=0; mb<4; ++mb){
    #pragma unroll
    for (int q=0; q<4; ++q){
      int rloc = wm*64 + mb*16 + rq + q;
      if (!SHARED && mt*128 + rloc >= cnt) continue;
      size_t orow = (size_t)(outbase + rloc);
      #pragma unroll
      for (int cg=0; cg<2; ++cg){
        float g = accg[mb][cg][q], u = accu[mb][cg][q];
        float sv = g / (1.0f + __expf(-g)) * u;   // silu(g)*u
        interm[orow*ID + (size_t)(nt*64 + wn*32 + cg*16 + fr)] = f2bf(sv);
      }
    }
  }
}

// ---------------- grouped down GEMM (r4-best config) -------------------------
// Block: 128 rows x 128 out-cols, 4 waves 2x2; wave = 64 rows x 64 cols.
template<bool SHARED>
__global__ __launch_bounds__(256,2)
void down_kernel(const ushort* __restrict__ interm, const float* __restrict__ WD,
                 const int* __restrict__ cntC, const int* __restrict__ ebase,
                 ushort* __restrict__ out_rows, float* __restrict__ outf)
{
  int e, mt, nt, cnt, abase;
  if (SHARED){
    nt = blockIdx.x & 7; mt = blockIdx.x >> 3; e = 0; cnt = TOK; abase = mt*128;
  } else {
    int x = blockIdx.x & 7; int rem = blockIdx.x >> 3;
    nt = rem & 7; mt = (rem >> 3) & 7; e = ((rem >> 6) << 3) | x;
    cnt = cntC[e];
    if (mt*128 >= cnt) return;
    abase = ebase[e] + mt*128;
  }
  const ushort* A = interm + (size_t)abase*ID;
  const float* wd = WD + (SHARED ? (size_t)0 : (size_t)e*HD*ID) + (size_t)nt*128*ID;

  __shared__ ushort aL[64*128];   // 16KB
  __shared__ float  bF[128*64];   // 32KB

  const int tid = threadIdx.x;
  const int w = tid >> 6, l = tid & 63;
  const int wm = w >> 1, wn = w & 1;
  const int fr = l & 15, fko = (l >> 4) * 8;

  const ushort* aSrc[4];
  #pragma unroll
  for (int j=0;j<4;++j){
    int f = j*256 + tid;
    int L = f >> 4, s = f & 15;
    int g = s ^ (L & 15);
    int row = 2*L + (g >> 3);
    aSrc[j] = A + (size_t)row*ID + (g & 7)*8;
  }
  const float* bSrc[8];
  #pragma unroll
  for (int j=0;j<8;++j){
    int f = j*256 + tid;
    int R = f >> 4, s = f & 15;
    int g = s ^ (R & 15);
    bSrc[j] = wd + (size_t)R*ID + g*4;
  }

  f32x4 acc[4][4];
  #pragma unroll
  for (int i=0;i<4;++i)
    #pragma unroll
    for (int j=0;j<4;++j) acc[i][j] = (f32x4)0.0f;

  auto stage = [&](int kc){
    #pragma unroll
    for (int j=0;j<4;++j) gld16(aL + (size_t)(j*256 + w*64)*8, aSrc[j] + kc);
    #pragma unroll
    for (int j=0;j<8;++j) gld16(bF + (size_t)(j*256 + w*64)*4, bSrc[j] + kc);
  };

  stage(0);
  for (int kc=0; kc<ID; kc+=64){
    __syncthreads();
    #pragma unroll
    for (int ks=0; ks<2; ++ks){
      s16x8 a[4];
      #pragma unroll
      for (int mb=0; mb<4; ++mb){
        int r = wm*64 + mb*16 + fr;
        int agl = ks*4 + (fko >> 3);
        int g = ((r & 1) << 3) | agl;
        int L = r >> 1;
        int gs = g ^ (L & 15);
        a[mb] = *(const s16x8*)&aL[L*128 + gs*8];
      }
      #pragma unroll
      for (int cg=0; cg<4; ++cg){
        int R = wn*64 + cg*16 + fr;
        int gl0 = ks*8 + (fko >> 2);
        int x0 = R*64 + ((gl0 ^ (R & 15)) * 4);
        int x1 = R*64 + (((gl0+1) ^ (R & 15)) * 4);
        s16x8 bd = pack8(*(const f32x4*)&bF[x0], *(const f32x4*)&bF[x1]);
        #pragma unroll
        for (int mb=0; mb<4; ++mb){
          acc[mb][cg] = __builtin_amdgcn_mfma_f32_16x16x32_bf16(a[mb], bd, acc[mb][cg], 0, 0, 0);
        }
      }
    }
    __syncthreads();
    if (kc + 64 < ID) stage(kc + 64);
  }

  const int rq = (l >> 4) * 4;
  #pragma unroll
  for (int mb=0; mb<4; ++mb){
    #pragma unroll
    for (int q=0; q<4; ++q){
      int rloc = wm*64 + mb*16 + rq + q;
      if (!SHARED && mt*128 + rloc >= cnt) continue;
      #pragma unroll
      for (int cg=0; cg<4; ++cg){
        float v = acc[mb][cg][q];
        int colg = nt*128 + wn*64 + cg*16 + fr;
        if (SHARED) outf[(size_t)(mt*128 + rloc)*HD + colg] = v;
        else        out_rows[(size_t)(abase + rloc)*HD + colg] = f2bf(v);
      }
    }
  }
}

// ---------------- combine: out += sum_k topw * routed_row --------------------
__global__ __launch_bounds__(256)
void combine_kernel(const int* __restrict__ topi, const float* __restrict__ topw,
                    const int* __restrict__ pos, const int* __restrict__ ebase,
                    const ushort* __restrict__ out_rows, float* __restrict__ out)
{
  const int t = blockIdx.x;
  const int tid = threadIdx.x;
  __shared__ int rws[TK];
  __shared__ float wts[TK];
  if (tid < TK){
    int e = topi[(size_t)t*TK + tid];
    int p = pos[(size_t)t*TK + tid];
    rws[tid] = (p < CAP) ? (ebase[e] + p) : -1;
    wts[tid] = topw[(size_t)t*TK + tid];
  }
  __syncthreads();
  const int h0 = tid * 4;
  float4 acc = *(float4*)(out + (size_t)t*HD + h0);
  #pragma unroll
  for (int k=0;k<TK;++k){
    int r = rws[k];
    if (r < 0) continue;
    ushort4 v = *(const ushort4*)(out_rows + (size_t)r*HD + h0);
    float wk = wts[k];
    acc.x += wk*bf2f(v.x); acc.y += wk*bf2f(v.y);
    acc.z += wk*bf2f(v.z); acc.w += wk*bf2f(v.w);
  }
  *(float4*)(out + (size_t)t*HD + h0) = acc;
}

// ---------------- launch ------------------------------------------------------
extern "C" void kernel_launch(void* const* d_in, const int* in_sizes, int n_in,
                              void* d_out, int out_size, void* d_ws, size_t ws_size,
                              hipStream_t stream)
{
  (void)in_sizes; (void)n_in; (void)out_size; (void)ws_size;
  const float* X   = (const float*)d_in[0];
  const float* GW  = (const float*)d_in[1];
  const float* SWG = (const float*)d_in[2];
  const float* SWU = (const float*)d_in[3];
  const float* SWD = (const float*)d_in[4];
  const float* EWG = (const float*)d_in[5];
  const float* EWU = (const float*)d_in[6];
  const float* EWD = (const float*)d_in[7];
  float* OUT = (float*)d_out;

  char* p = (char*)d_ws;
  int*    topi    = (int*)p;      p += (size_t)NROUTE*4;
  float*  topw    = (float*)p;    p += (size_t)NROUTE*4;
  int*    pos     = (int*)p;      p += (size_t)NROUTE*4;
  int*    ccnt    = (int*)p;      p += (size_t)NCHUNK*NE*4;
  int*    cbase   = (int*)p;      p += (size_t)NCHUNK*NE*4;
  int*    cntC    = (int*)p;      p += 256;
  int*    ebase   = (int*)p;      p += 512;
  int*    rowlist = (int*)p;      p += (size_t)NE*CAP*4;
  ushort* Xbf     = (ushort*)p;   p += (size_t)TOK*HD*2;
  ushort* interm_r= (ushort*)p;   p += (size_t)(NROUTE+128)*ID*2;
  ushort* interm_s= (ushort*)p;   p += (size_t)TOK*ID*2;
  ushort* out_rows= (ushort*)p;   p += (size_t)NROUTE*HD*2;

  cvtX_kernel<<<TOK*HD/8/256, 256, 0, stream>>>(X, Xbf);
  gating_kernel<<<256, 256, 0, stream>>>(X, GW, topi, topw);
  hist_kernel<<<NCHUNK, 256, 0, stream>>>(topi, ccnt);
  scan_kernel<<<1, 64, 0, stream>>>(ccnt, cbase, cntC, ebase);
  assign_kernel<<<NCHUNK, 64, 0, stream>>>(topi, cbase, pos, rowlist);

  gateup_kernel<false><<<4096, 256, 0, stream>>>(Xbf, EWG, EWU, rowlist, cntC, ebase, interm_r);
  gateup_kernel<true ><<<256,  256, 0, stream>>>(Xbf, SWG, SWU, nullptr, nullptr, nullptr, interm_s);
  down_kernel<false><<<4096, 256, 0, stream>>>(interm_r, EWD, cntC, ebase, out_rows, nullptr);
  down_kernel<true ><<<256,  256, 0, stream>>>(interm_s, SWD, nullptr, nullptr, nullptr, OUT);

  combine_kernel<<<TOK, 256, 0, stream>>>(topi, topw, pos, ebase, out_rows, OUT);
}